// Round 6
// baseline (199.935 us; speedup 1.0000x reference)
//
#include <hip/hip_runtime.h>

// Boundary_binaryLoss: 15x15 binary morphology boundary mask + masked NLL mean.
// B=32, C=2, H=480, W=864. logits [B,C,H,W] f32, labels [B,H,W] i32 in {0,1,255}.
//
// valid(b,h,w) = (label != 255) && (clipped 15x15 window has a px with
//   np_label==0 (label 0 or 255) AND a px with np_label==255 (label 1))
// loss = -sum(valid ? logits[b,label,h,w] : 0) / max(#valid, 1)
//
// R1..R6 history: atomics->partials (66us); reg-prefetch sunk (66); lds-DMA
//     drained by barrier (65); barrier-free scalar (65); fat-load spill
//     (91, WRITE 130MB); fat-load fused spill-free (63, occ 25%).
// R7: TH=32 1-wave tiles: FETCH 122->82MB but only 1920 waves -> starved
//     (occ 21%, 102us). KEY FACT across all rounds: warm-cache profiler
//     replays (FETCH~0) run at IDENTICAL duration => limit is L2/L3-path
//     line traffic, ~4.6 TB/s effective when wave-fed (R6), collapsing when
//     starved. Lever: touched bytes x parallelism simultaneously.
// R8: block-cooperative labels + wave-streamed logits, ONE barrier:
//     - 256-thr block = 32x216 tile; 46 halo label rows loaded once per
//       block (waves split rows 12/12/12/10, fused int4 load+fold as R6)
//     - h-flags(2b) + center(chan,ign 2b) packed per-px nibbles -> u16
//       LDS plane [64 lanes][50 rows] (6.4KB, 25*lane%32 conflict-free)
//     - logits (16 float4/wave) issued BEFORE labels: vmcnt retires
//       in-order => last label fold implies logits landed => the barrier's
//       vmcnt(0) drain is free (R3 lesson inverted)
//     - post-barrier: 12 ds_read_b32 -> 192-bit bytewise shift-OR fold
//       (vertical 15-OR), select, reduce. Labels 6.8 B/px (was 13),
//       logits 8.9 => ~207MB touched at 7680 waves, ~4/SIMD resident.
//     Predict: main 63->~44us, FETCH~105MB, WRITE~60KB (spill tripwire).

namespace {
constexpr int B_ = 32;
constexpr int H_ = 480;
constexpr int W_ = 864;
constexpr int HW = H_ * W_;
constexpr int R_ = 7;
constexpr int TH_ = 32;                  // output rows per block
constexpr int LH = TH_ + 2 * R_;         // 46 halo rows
constexpr int SW = 216;                  // output cols per block
constexpr int NSX = W_ / SW;             // 4
constexpr int NSY = H_ / TH_;            // 15
constexpr int NBLK = B_ * NSY * NSX;     // 1920 blocks
constexpr int ROWP = 50;                 // padded row count (25*lane%32 banks)
} // namespace

typedef unsigned long long u64;

extern "C" __global__ __launch_bounds__(256, 4)
void boundary_loss_main(const float* __restrict__ logits,
                        const int* __restrict__ labels,
                        double2* __restrict__ partials)
{
  __shared__ unsigned short plane[64][ROWP];   // [hbyte | cbyte<<8] per (lane,row)
  __shared__ double red_s[4];
  __shared__ unsigned red_c[4];

  const int tid = threadIdx.x;
  const int lane = tid & 63;
  const int wv = tid >> 6;
  const int bid = blockIdx.x;
  // bijective XCD swizzle (1920 % 8 == 0): each XCD gets 4 complete images;
  // sy-adjacent tiles co-resident -> halo label rows L2-hit.
  const int lb = (bid & 7) * (NBLK / 8) + (bid >> 3);
  const int b = lb / (NSY * NSX);
  const int rr = lb - b * (NSY * NSX);
  const int sy = rr >> 2;                     // NSX == 4
  const int sx = rr & 3;
  const int gr0 = sy * TH_;
  const int colbase = sx * SW;

  const int* __restrict__ lab = labels + b * HW;
  const float* __restrict__ lg = logits + (size_t)(2 * b) * HW;

  // ---- logits prefetch FIRST: 16 float4/wave, in flight during the whole
  //      label phase; in-order vmcnt retirement => free barrier drain ----
  const bool outl = (lane >= 2) && (lane < 56);   // 54 lanes x 4 = 216 cols
  float4 ga[8], gc[8];
  {
    const float* pg = lg + (size_t)(gr0 + 8 * wv) * W_ + (colbase + 4 * (lane - 2));
    if (outl) {
#pragma unroll
      for (int o = 0; o < 8; ++o) {
        ga[o] = *(const float4*)(pg + (size_t)o * W_);
        gc[o] = *(const float4*)(pg + (size_t)o * W_ + HW);
      }
    }
  }

  // ---- label halo: wave wv loads rows [12wv, 12wv+nr), fused fold ----
  const int r_lo = 12 * wv;
  const int nr = (wv == 3) ? 10 : 12;
  const int cb0 = colbase - 8 + 4 * lane;     // lanes 0..57 cover 232 cols
  const bool labok = (lane < 58) && (cb0 >= 0) && (cb0 + 3 < W_);
  const int* labp = lab + (labok ? cb0 : 0);

  // f: 2 bits/row (bit0 np==0 i.e. label 0/255, bit1 np==255 i.e. label 1)
  // c: 2 bits/row (bit0 label==1 -> chan, bit1 label==255 -> ignore)
  unsigned f0 = 0, f1 = 0, f2 = 0, f3 = 0;
  unsigned c0 = 0, c1 = 0, c2 = 0, c3 = 0;
#pragma unroll
  for (int k = 0; k < 12; ++k) {
    if (k < nr) {
      const int a = r_lo + k;
      const int gr = gr0 - R_ + a;
      const bool rowok = (gr >= 0) && (gr < H_);
      const int grc = rowok ? gr : (gr < 0 ? 0 : H_ - 1);
      const int4 v = *(const int4*)(labp + grc * W_);
      const unsigned m = (labok && rowok) ? 3u : 0u;
      const int sh = 2 * k;
      f0 |= (((v.x == 1) ? 2u : 1u) & m) << sh;
      f1 |= (((v.y == 1) ? 2u : 1u) & m) << sh;
      f2 |= (((v.z == 1) ? 2u : 1u) & m) << sh;
      f3 |= (((v.w == 1) ? 2u : 1u) & m) << sh;
      c0 |= (((v.x == 1) ? 1u : 0u) | ((v.x == 255) ? 2u : 0u)) << sh;
      c1 |= (((v.y == 1) ? 1u : 0u) | ((v.y == 255) ? 2u : 0u)) << sh;
      c2 |= (((v.z == 1) ? 1u : 0u) | ((v.z == 255) ? 2u : 0u)) << sh;
      c3 |= (((v.w == 1) ? 1u : 0u) | ((v.w == 255) ? 2u : 0u)) << sh;
    }
  }

  // ---- horizontal 15-OR (exact per column over 4-col lanes, as R6) ----
  // col 4l+0: sfx3(l-2)|all(l-1..l+1)       col 4l+1: sfx2|core|pfx1(l+2)
  // col 4l+2: sfx1|core|pfx2(l+2)           col 4l+3: all(l-1..l+1)|pfx3
  // garbage reaches only lanes outside [2,56) -> never consumed.
  const unsigned allf = f0 | f1 | f2 | f3;
  const unsigned s2 = f2 | f3, s3 = f1 | s2;
  const unsigned p2 = f0 | f1, p3 = p2 | f2;
  const unsigned core = __shfl_up(allf, 1, 64) | allf | __shfl_down(allf, 1, 64);
  const unsigned w0 = core | __shfl_up(s3, 2, 64);
  const unsigned w1 = core | __shfl_up(s2, 2, 64) | __shfl_down(f0, 2, 64);
  const unsigned w2 = core | __shfl_up(f3, 2, 64) | __shfl_down(p2, 2, 64);
  const unsigned w3 = core | __shfl_down(p3, 2, 64);

  // ---- publish h-flags + center nibbles to LDS ----
#pragma unroll
  for (int k = 0; k < 12; ++k) {
    if (k < nr) {
      const int sh = 2 * k;
      const unsigned hb = ((w0 >> sh) & 3u) | (((w1 >> sh) & 3u) << 2) |
                          (((w2 >> sh) & 3u) << 4) | (((w3 >> sh) & 3u) << 6);
      const unsigned cby = ((c0 >> sh) & 3u) | (((c1 >> sh) & 3u) << 2) |
                           (((c2 >> sh) & 3u) << 4) | (((c3 >> sh) & 3u) << 6);
      plane[lane][r_lo + k] = (unsigned short)(hb | (cby << 8));
    }
  }
  __syncthreads();   // vmcnt(0) drain is free: logits retired before labels

  // ---- read back rows [8wv, 8wv+24) : 12 conflict-free ds_read_b32 ----
  unsigned q[12];
  {
    const unsigned* pq = (const unsigned*)&plane[lane][8 * wv];
#pragma unroll
    for (int i = 0; i < 12; ++i) q[i] = pq[i];
  }

  // ---- vertical 15-OR: 192-bit byte-wise shift-OR fold ----
#define HP(i) ((u64)((q[i] & 0xFFu) | ((q[i] >> 8) & 0xFF00u)))
#define CPAIR(i) ((u64)(((q[i] >> 8) & 0xFFu) | ((q[i] >> 24) << 8)))
  u64 L = HP(0) | (HP(1) << 16) | (HP(2) << 32) | (HP(3) << 48);   // rows 0..7
  u64 M = HP(4) | (HP(5) << 16) | (HP(6) << 32) | (HP(7) << 48);   // rows 8..15
  u64 Hh = HP(8) | (HP(9) << 16) | (HP(10) << 32) | (HP(11) << 48); // 16..23
  L |= (L >> 8) | (M << 56);   M |= (M >> 8) | (Hh << 56);   Hh |= Hh >> 8;
  L |= (L >> 16) | (M << 48);  M |= (M >> 16) | (Hh << 48);
  L |= (L >> 32) | (M << 32);  M |= (M >> 32) | (Hh << 32);
  const u64 F = L | (L >> 56) | (M << 8);   // byte o = OR rows o..o+14
  // center bytes for output rows: rel rows 7..14
  const u64 C = (u64)(q[3] >> 24)
              | (CPAIR(4) << 8) | (CPAIR(5) << 24) | (CPAIR(6) << 40)
              | ((u64)((q[7] >> 8) & 0xFFu) << 56);
#undef HP
#undef CPAIR

  // ---- select prefetched logits + accumulate ----
  double lsum = 0.0;
  unsigned lcnt = 0;
  if (outl) {
#pragma unroll
    for (int o = 0; o < 8; ++o) {
      const unsigned Fb = (unsigned)(F >> (8 * o)) & 0xFFu;
      const unsigned Cb = (unsigned)(C >> (8 * o)) & 0xFFu;
      const float4 A = ga[o], Cc = gc[o];
      const bool k0 = ((Fb & 3u) == 3u) && !(Cb & 2u);
      const bool k1 = (((Fb >> 2) & 3u) == 3u) && !((Cb >> 2) & 2u);
      const bool k2 = (((Fb >> 4) & 3u) == 3u) && !((Cb >> 4) & 2u);
      const bool k3 = (((Fb >> 6) & 3u) == 3u) && !((Cb >> 6) & 2u);
      lsum += k0 ? (double)((Cb & 1u) ? Cc.x : A.x) : 0.0;
      lsum += k1 ? (double)(((Cb >> 2) & 1u) ? Cc.y : A.y) : 0.0;
      lsum += k2 ? (double)(((Cb >> 4) & 1u) ? Cc.z : A.z) : 0.0;
      lsum += k3 ? (double)(((Cb >> 6) & 1u) ? Cc.w : A.w) : 0.0;
      lcnt += (unsigned)k0 + k1 + k2 + k3;
    }
  }

  // ---- wave + block reduction -> one double2 per block ----
#pragma unroll
  for (int off = 32; off > 0; off >>= 1) {
    lsum += __shfl_down(lsum, off, 64);
    lcnt += __shfl_down(lcnt, off, 64);
  }
  if ((tid & 63) == 0) { red_s[wv] = lsum; red_c[wv] = lcnt; }
  __syncthreads();
  if (tid == 0) {
    const double s = red_s[0] + red_s[1] + red_s[2] + red_s[3];
    const double c = (double)(red_c[0] + red_c[1] + red_c[2] + red_c[3]);
    partials[bid] = make_double2(s, c);
  }
}

extern "C" __global__ __launch_bounds__(1024)
void boundary_loss_final(const double2* __restrict__ partials,
                         float* __restrict__ out)
{
  __shared__ double red_s[16];
  __shared__ double red_c[16];
  const int tid = threadIdx.x;
  double s = 0.0, c = 0.0;
  for (int i = tid; i < NBLK; i += 1024) {
    const double2 p = partials[i];
    s += p.x;
    c += p.y;
  }
#pragma unroll
  for (int off = 32; off > 0; off >>= 1) {
    s += __shfl_down(s, off, 64);
    c += __shfl_down(c, off, 64);
  }
  const int wave = tid >> 6;
  if ((tid & 63) == 0) { red_s[wave] = s; red_c[wave] = c; }
  __syncthreads();
  if (tid == 0) {
    double ts = 0.0, tc = 0.0;
#pragma unroll
    for (int i = 0; i < 16; ++i) { ts += red_s[i]; tc += red_c[i]; }
    if (tc < 1.0) tc = 1.0;
    out[0] = (float)(-ts / tc);
  }
}

extern "C" void kernel_launch(void* const* d_in, const int* in_sizes, int n_in,
                              void* d_out, int out_size, void* d_ws, size_t ws_size,
                              hipStream_t stream)
{
  const float* logits = (const float*)d_in[0];
  const int* labels = (const int*)d_in[1];
  float* out = (float*)d_out;
  double2* partials = (double2*)d_ws;  // NBLK*16 B = 30,720 B; every slot
                                       // written by main -> no init needed.

  boundary_loss_main<<<dim3(NBLK), 256, 0, stream>>>(logits, labels, partials);
  boundary_loss_final<<<1, 1024, 0, stream>>>(partials, out);
}

// Round 7
// 194.034 us; speedup vs baseline: 1.0304x; 1.0304x over previous
//
#include <hip/hip_runtime.h>

// Boundary_binaryLoss: 15x15 binary morphology boundary mask + masked NLL mean.
// B=32, C=2, H=480, W=864. logits [B,C,H,W] f32, labels [B,H,W] i32 in {0,1,255}.
//
// valid(b,h,w) = (label != 255) && (clipped 15x15 window has a px with
//   np_label==0 (label 0 or 255) AND a px with np_label==255 (label 1))
// loss = -sum(valid ? logits[b,label,h,w] : 0) / max(#valid, 1)
//
// R1..R5: atomics->partials (66); reg-prefetch sunk (66); lds-DMA drained by
//     barrier (65); barrier-free scalar (65); fat-load spill (91, WRITE 130MB).
// R6: fat loads, fused fold, spill-free, independent waves: 63us. Effective
//     BW 292MB/63us = 4.6 TB/s -- best ever observed.
// R7: TH=32 1-wave: bytes down but 1920 waves starved -> 2.1 TB/s, 102us.
// R8: block-coop labels (bytes 182MB) but barrier coupling -> 2.65 TB/s, 69us.
// UNIFIED MODEL: working set 159MB >> 32MB L2, fits L3. Every L2-miss crosses
//     the XCD<->InfinityCache fabric which saturates ~4.6 TB/s (warm replays
//     identical; occupancy/width/barriers irrelevant once queue-saturated).
//     dur ~= fabric-bytes / 4.6TB/s. Lever: serve re-reads from XCD-local L2.
// R9: R6 VERBATIM + bijective XCD swizzle. One image's labels = 1.66MB < 4MB
//     XCD L2. XCD k gets blocks [240k, 240k+240) = 4 whole images in sy-major
//     order; vertical-neighbor tiles (sharing 14 halo rows) become
//     consecutive blocks ON THE SAME XCD -> halo re-reads (133MB) become L2
//     hits instead of fabric crossings. Fabric: 292 -> ~159MB.
//     Predict: main 63 -> 40-47us; FETCH/WRITE/VGPR/occ unchanged.
//     If main stays 62-66: fabric theory falsified -> TCC_HIT two-pass next.

namespace {
constexpr int B_ = 32;
constexpr int H_ = 480;
constexpr int W_ = 864;
constexpr int HW = H_ * W_;
constexpr int R_ = 7;
constexpr int TH_ = 8;                   // output rows per wave
constexpr int LH = TH_ + 2 * R_;         // 22 label rows read
constexpr int SW = 216;                  // output cols per strip
constexpr int NSX = W_ / SW;             // 4 (exact -> no overlap)
constexpr int NSY = H_ / TH_;            // 60
constexpr int WPB = 4;                   // waves per block
constexpr int NTILE = B_ * NSY * NSX;    // 7680 wave-tiles
constexpr int NBLKP = NTILE / WPB;       // 1920 blocks (1920 % 8 == 0)
} // namespace

__device__ __forceinline__ unsigned long long shfl_up64(unsigned long long x, int d) {
  return __shfl_up(x, d, 64);
}
__device__ __forceinline__ unsigned long long shfl_dn64(unsigned long long x, int d) {
  return __shfl_down(x, d, 64);
}

extern "C" __global__ __launch_bounds__(256, 2)
void boundary_loss_main(const float* __restrict__ logits,
                        const int* __restrict__ labels,
                        double2* __restrict__ partials)
{
  __shared__ double red_s[WPB];
  __shared__ unsigned red_c[WPB];

  const int tid = threadIdx.x;
  const int lane = tid & 63;
  const int wv = tid >> 6;
  // ---- R9: bijective XCD swizzle (blocks dispatch round-robin over 8 XCDs;
  //      bid%8 = XCD). XCD k owns lb in [240k, 240k+240) = 4 complete images,
  //      sy-major: consecutive blocks on one XCD are vertical neighbors ->
  //      14 shared halo label rows hit XCD-local L2, not the fabric. ----
  const int lb = (blockIdx.x & 7) * (NBLKP / 8) + (blockIdx.x >> 3);
  const int t = lb * WPB + wv;                // wave-tile id
  const int b = t / (NSY * NSX);
  const int rr = t - b * (NSY * NSX);
  const int sy = rr >> 2;                     // NSX == 4
  const int sx = rr & 3;

  const int gr0 = sy * TH_;                   // first output image row
  const int wb = sx * SW - 8;                 // window col base (lane 0, j 0)
  const int cb0 = wb + 4 * lane;              // this lane's 4-col base
  const bool colinb = (cb0 >= 0) && (cb0 + 3 < W_);   // W%4==0: all-or-none
  const int cbc = colinb ? cb0 : (cb0 < 0 ? 0 : W_ - 4);

  const int* __restrict__ lab = labels + b * HW + cbc;
  const float* __restrict__ lg = logits + (size_t)(2 * b) * HW;

  // ---- phase 1: FUSED label load+fold. 22 independent int4 loads (1KB/wave
  //      requests); immediate consumption lets the compiler pipeline issue
  //      depth against its register budget instead of spilling. ----
  // f[j]: 2 bits per label row (bit0: np==0 i.e. label 0/255; bit1: np==255
  // i.e. label 1). c[j]: 2 bits per OUTPUT row (bit0: label==1, bit1: ignore)
  unsigned long long f0 = 0, f1 = 0, f2 = 0, f3 = 0;
  unsigned cp0 = 0, cp1 = 0, cp2 = 0, cp3 = 0;
#pragma unroll
  for (int a = 0; a < LH; ++a) {
    int gr = gr0 - R_ + a;
    gr = gr < 0 ? 0 : (gr >= H_ ? H_ - 1 : gr);   // clamped; masked below
    const int4 v = *(const int4*)(lab + gr * W_);
    const unsigned e1x = (v.x == 1), e1y = (v.y == 1),
                   e1z = (v.z == 1), e1w = (v.w == 1);
    f0 |= (unsigned long long)(1u + e1x) << (2 * a);
    f1 |= (unsigned long long)(1u + e1y) << (2 * a);
    f2 |= (unsigned long long)(1u + e1z) << (2 * a);
    f3 |= (unsigned long long)(1u + e1w) << (2 * a);
    if (a >= R_ && a < R_ + TH_) {
      const int sh = 2 * (a - R_);
      cp0 |= (e1x | ((unsigned)(v.x == 255) << 1)) << sh;
      cp1 |= (e1y | ((unsigned)(v.y == 255) << 1)) << sh;
      cp2 |= (e1z | ((unsigned)(v.z == 255) << 1)) << sh;
      cp3 |= (e1w | ((unsigned)(v.w == 255) << 1)) << sh;
    }
  }
  // clip: OOB image rows / OOB lane columns contribute nothing
  {
    const int tv = gr0 == 0 ? R_ : 0;                   // invalid top rows
    const int hi = LH < (487 - gr0) ? LH : (487 - gr0); // first invalid bottom
    unsigned long long rm = ((1ull << (2 * (hi - tv))) - 1ull) << (2 * tv);
    if (!colinb) rm = 0;
    f0 &= rm; f1 &= rm; f2 &= rm; f3 &= rm;
  }

  // ---- phase 2: issue ALL logits loads (the one deliberate big live set:
  //      16 float4 = 64 VGPR); latency hides under phases 3-4 ----
  const bool outl = (lane >= 2) && (lane < 56);   // 54 lanes x 4 = 216 cols
  float4 g0[TH_], g1[TH_];
  if (outl) {
    const float* pg = lg + (size_t)gr0 * W_ + cb0;
#pragma unroll
    for (int o = 0; o < TH_; ++o) {
      g0[o] = *(const float4*)(pg + o * W_);
      g1[o] = *(const float4*)(pg + o * W_ + HW);
    }
  }

  // ---- phase 3: horizontal 15-OR, exact per column over 4-col lanes ----
  // col 4l+j window [4l+j-7, 4l+j+7]:
  //  j=0: sfx3(l-2)|all(l-1..l+1)
  //  j=1: sfx2(l-2)|core|pfx1(l+2)   j=2: sfx1(l-2)|core|pfx2(l+2)
  //  j=3:          all(l-1..l+1)|pfx3(l+2)
  // shuffle garbage only reaches lanes outside [2,56) -> never consumed.
  const unsigned long long allf = f0 | f1 | f2 | f3;
  const unsigned long long s2 = f2 | f3, s3 = f1 | s2;
  const unsigned long long p2 = f0 | f1, p3 = p2 | f2;
  const unsigned long long core =
      shfl_up64(allf, 1) | allf | shfl_dn64(allf, 1);
  unsigned long long w0 = core | shfl_up64(s3, 2);
  unsigned long long w1 = core | shfl_up64(s2, 2) | shfl_dn64(f0, 2);
  unsigned long long w2 = core | shfl_up64(f3, 2) | shfl_dn64(p2, 2);
  unsigned long long w3 = core | shfl_dn64(p3, 2);

  // ---- phase 4: vertical 15-OR (bit 2o = OR over label rows o..o+14) ----
  w0 |= w0 >> 2;  w0 |= w0 >> 4;  w0 |= w0 >> 8;  w0 |= w0 >> 14;
  w1 |= w1 >> 2;  w1 |= w1 >> 4;  w1 |= w1 >> 8;  w1 |= w1 >> 14;
  w2 |= w2 >> 2;  w2 |= w2 >> 4;  w2 |= w2 >> 8;  w2 |= w2 >> 14;
  w3 |= w3 >> 2;  w3 |= w3 >> 4;  w3 |= w3 >> 8;  w3 |= w3 >> 14;

  // ---- phase 5: select + accumulate ----
  double lsum = 0.0;
  unsigned lcnt = 0;
  if (outl) {
#pragma unroll
    for (int o = 0; o < TH_; ++o) {
      const unsigned b0 = (unsigned)(w0 >> (2 * o)) & 3u;
      const unsigned b1 = (unsigned)(w1 >> (2 * o)) & 3u;
      const unsigned b2 = (unsigned)(w2 >> (2 * o)) & 3u;
      const unsigned b3 = (unsigned)(w3 >> (2 * o)) & 3u;
      const unsigned q0 = (cp0 >> (2 * o)) & 3u;
      const unsigned q1 = (cp1 >> (2 * o)) & 3u;
      const unsigned q2 = (cp2 >> (2 * o)) & 3u;
      const unsigned q3 = (cp3 >> (2 * o)) & 3u;
      const float4 a = g0[o], c = g1[o];
      const bool k0 = (b0 == 3u) && !(q0 & 2u);
      const bool k1 = (b1 == 3u) && !(q1 & 2u);
      const bool k2 = (b2 == 3u) && !(q2 & 2u);
      const bool k3 = (b3 == 3u) && !(q3 & 2u);
      lsum += k0 ? (double)((q0 & 1u) ? c.x : a.x) : 0.0;
      lsum += k1 ? (double)((q1 & 1u) ? c.y : a.y) : 0.0;
      lsum += k2 ? (double)((q2 & 1u) ? c.z : a.z) : 0.0;
      lsum += k3 ? (double)((q3 & 1u) ? c.w : a.w) : 0.0;
      lcnt += (unsigned)k0 + k1 + k2 + k3;
    }
  }

  // ---- wave + block reduction -> one double2 per block ----
#pragma unroll
  for (int off = 32; off > 0; off >>= 1) {
    lsum += __shfl_down(lsum, off, 64);
    lcnt += __shfl_down(lcnt, off, 64);
  }
  if ((tid & 63) == 0) { red_s[wv] = lsum; red_c[wv] = lcnt; }
  __syncthreads();                            // tail-only
  if (tid == 0) {
    const double s = red_s[0] + red_s[1] + red_s[2] + red_s[3];
    const double c = (double)(red_c[0] + red_c[1] + red_c[2] + red_c[3]);
    partials[blockIdx.x] = make_double2(s, c);
  }
}

extern "C" __global__ __launch_bounds__(1024)
void boundary_loss_final(const double2* __restrict__ partials,
                         float* __restrict__ out)
{
  __shared__ double red_s[16];
  __shared__ double red_c[16];
  const int tid = threadIdx.x;
  double s = 0.0, c = 0.0;
  for (int i = tid; i < NBLKP; i += 1024) {
    const double2 p = partials[i];
    s += p.x;
    c += p.y;
  }
#pragma unroll
  for (int off = 32; off > 0; off >>= 1) {
    s += __shfl_down(s, off, 64);
    c += __shfl_down(c, off, 64);
  }
  const int wave = tid >> 6;
  if ((tid & 63) == 0) { red_s[wave] = s; red_c[wave] = c; }
  __syncthreads();
  if (tid == 0) {
    double ts = 0.0, tc = 0.0;
#pragma unroll
    for (int i = 0; i < 16; ++i) { ts += red_s[i]; tc += red_c[i]; }
    if (tc < 1.0) tc = 1.0;
    out[0] = (float)(-ts / tc);
  }
}

extern "C" void kernel_launch(void* const* d_in, const int* in_sizes, int n_in,
                              void* d_out, int out_size, void* d_ws, size_t ws_size,
                              hipStream_t stream)
{
  const float* logits = (const float*)d_in[0];
  const int* labels = (const int*)d_in[1];
  float* out = (float*)d_out;
  double2* partials = (double2*)d_ws;  // NBLKP*16 B = 30,720 B; every slot
                                       // written by main -> no init needed.

  boundary_loss_main<<<dim3(NBLKP), 256, 0, stream>>>(logits, labels, partials);
  boundary_loss_final<<<1, 1024, 0, stream>>>(partials, out);
}